// Round 2
// baseline (762.099 us; speedup 1.0000x reference)
//
#include <hip/hip_runtime.h>

// QRotationCrossAttention on MI355X (gfx950)
// B=4, C=512, Q=4, H=W=64 -> S = 16384, G = 128, heads = 4
//
// Round 2: double-buffered LDS (T3-minimum: stage(next) BEFORE compute, one
// barrier per K-tile), XOR granule swizzle (linear LDS dest + inverse-swizzled
// global source + swizzled ds_read), head-grouped q/k layout, split-K logits
// with non-atomic partials, IQBN stats fused into o2 epilogue.

#define DEVI __device__ __forceinline__
typedef unsigned short u16;
typedef __bf16 bf16x8 __attribute__((ext_vector_type(8)));
typedef float f32x4 __attribute__((ext_vector_type(4)));

DEVI float bf2f(unsigned int u) {
  union { unsigned int u; float f; } v; v.u = u << 16; return v.f;
}
DEVI u16 f2bf(float f) {
  union { float f; unsigned int u; } v; v.f = f;
  unsigned int r = v.u + 0x7FFFu + ((v.u >> 16) & 1u);
  return (u16)(r >> 16);
}
DEVI void gload_lds16(const void* gp, void* lp) {
  __builtin_amdgcn_global_load_lds((const __attribute__((address_space(1))) int*)gp,
                                   (__attribute__((address_space(3))) int*)lp, 16, 0, 0);
}

// ---------------- weight converts ----------------
__global__ __launch_bounds__(256) void cvtW_k(const float* __restrict__ Wq, const float* __restrict__ Wk,
                                              const float* __restrict__ Wa1, u16* __restrict__ WQB,
                                              u16* __restrict__ WKB, u16* __restrict__ WA1B) {
  int i = blockIdx.x * 256 + threadIdx.x;  // < 147456
  const float* src; u16* dst; int off;
  if (i < 65536) { src = Wq; dst = WQB; off = i; }
  else if (i < 131072) { src = Wk; dst = WKB; off = i - 65536; }
  else { src = Wa1; dst = WA1B; off = i - 131072; }
  float4 v = reinterpret_cast<const float4*>(src)[off];
  ushort4 o; o.x = f2bf(v.x); o.y = f2bf(v.y); o.z = f2bf(v.z); o.w = f2bf(v.w);
  reinterpret_cast<ushort4*>(dst)[off] = o;
}

// in[b][r][c] fp32 -> out[b][c][r] bf16
__global__ __launch_bounds__(256) void transpose_cvt(const float* __restrict__ in, u16* __restrict__ out,
                                                     int R, int Cc, long sIn, long sOut) {
  __shared__ float tile[64][65];
  const int t = threadIdx.x;
  const int c0 = blockIdx.x * 64, r0 = blockIdx.y * 64, b = blockIdx.z;
  const float* ip = in + (long)b * sIn;
  u16* op = out + (long)b * sOut;
#pragma unroll
  for (int i = 0; i < 4; ++i) {
    int r = (t >> 4) + i * 16;
    int c = (t & 15) * 4;
    float4 v = *reinterpret_cast<const float4*>(ip + (long)(r0 + r) * Cc + c0 + c);
    tile[r][c] = v.x; tile[r][c + 1] = v.y; tile[r][c + 2] = v.z; tile[r][c + 3] = v.w;
  }
  __syncthreads();
#pragma unroll
  for (int i = 0; i < 4; ++i) {
    int c = (t >> 4) + i * 16;
    int r = (t & 15) * 4;
    ushort4 o;
    o.x = f2bf(tile[r][c]); o.y = f2bf(tile[r + 1][c]);
    o.z = f2bf(tile[r + 2][c]); o.w = f2bf(tile[r + 3][c]);
    *reinterpret_cast<ushort4*>(op + (long)(c0 + c) * R + r0 + r) = o;
  }
}

// Woh[h][o][g] = bf16(Wo[o][4g+h])
__global__ __launch_bounds__(256) void woh_k(const float* __restrict__ Wo, u16* __restrict__ Woh) {
  int idx = blockIdx.x * 256 + threadIdx.x;  // < 262144
  int h = idx >> 16;
  int o = (idx >> 7) & 511;
  int g = idx & 127;
  union { float f; unsigned int u; } v; v.f = Wo[(long)o * 512 + 4 * g + h];
  unsigned int r = v.u + 0x7FFFu + ((v.u >> 16) & 1u);
  Woh[idx] = (u16)(r >> 16);
}

// ---------------- MFMA GEMM core: C[M,N] = A[M,K] @ Bt[N,K]^T ----------------
// dbuf LDS, granule XOR-swizzle, single barrier per K-tile.
enum { MODE_GATE = 0, MODE_BIAS = 1, MODE_PLAIN = 2, MODE_FOLD1 = 3 };

template <int MODE>
__global__ __launch_bounds__(256, 2) void gemm_bt(const u16* __restrict__ A, const u16* __restrict__ Bt,
                                                  u16* __restrict__ C, const float* __restrict__ bias,
                                                  const float* __restrict__ aw, float* __restrict__ stata,
                                                  int M, int N, int K, long sA, long sB, long sC) {
  __shared__ u16 As[2][128 * 64];
  __shared__ u16 Bs[2][128 * 64];
  __shared__ float racc[128][2];
  const int t = threadIdx.x;
  const int bn = blockIdx.x, bm = blockIdx.y, bz = blockIdx.z;
  const u16* Ab; const u16* Bb;
  if constexpr (MODE == MODE_FOLD1) {
    Ab = A + (long)(bz & 3) * 512 * 128;
    Bb = Bt + (long)bz * 128 * 128;
  } else {
    Ab = A + (long)bz * sA;
    Bb = Bt + (long)bz * sB;
  }
  const u16* Atile = Ab + (long)(bm * 128) * K;
  const u16* Btile = Bb + (long)(bn * 128) * K;
  const int wid = t >> 6, l = t & 63;
  const int rbase = (wid >> 1) * 64, cbase = (wid & 1) * 64;
  const int lr = l & 15, hi = l >> 4;
  f32x4 acc[4][4] = {};
  const int nt = K >> 6;

  // prologue stage into buf 0 (linear LDS dest, inverse-swizzled global src)
#pragma unroll
  for (int i = 0; i < 4; ++i) {
    int idx = t + i * 256;
    int r = idx >> 3;
    int gs = ((idx & 7) ^ (r & 7)) * 8;
    gload_lds16(Atile + (long)r * K + gs, &As[0][idx * 8]);
    gload_lds16(Btile + (long)r * K + gs, &Bs[0][idx * 8]);
  }
  __syncthreads();
  int cur = 0;
  for (int kt = 0; kt < nt; ++kt) {
    if (kt + 1 < nt) {
      int koff = (kt + 1) << 6;
#pragma unroll
      for (int i = 0; i < 4; ++i) {
        int idx = t + i * 256;
        int r = idx >> 3;
        int gs = ((idx & 7) ^ (r & 7)) * 8;
        gload_lds16(Atile + (long)r * K + koff + gs, &As[cur ^ 1][idx * 8]);
        gload_lds16(Btile + (long)r * K + koff + gs, &Bs[cur ^ 1][idx * 8]);
      }
    }
#pragma unroll
    for (int s = 0; s < 2; ++s) {
      bf16x8 av[4], bv[4];
#pragma unroll
      for (int m = 0; m < 4; ++m) {
        int ra = rbase + m * 16 + lr;
        av[m] = *reinterpret_cast<const bf16x8*>(&As[cur][ra * 64 + ((4 * s + hi) ^ (ra & 7)) * 8]);
      }
#pragma unroll
      for (int n = 0; n < 4; ++n) {
        int rb = cbase + n * 16 + lr;
        bv[n] = *reinterpret_cast<const bf16x8*>(&Bs[cur][rb * 64 + ((4 * s + hi) ^ (rb & 7)) * 8]);
      }
#pragma unroll
      for (int m = 0; m < 4; ++m)
#pragma unroll
        for (int n = 0; n < 4; ++n)
          acc[m][n] = __builtin_amdgcn_mfma_f32_16x16x32_bf16(av[m], bv[n], acc[m][n], 0, 0, 0);
    }
    __syncthreads();
    cur ^= 1;
  }

  int qq = 0;
  if constexpr (MODE == MODE_BIAS) {
    if (t < 128) { racc[t][0] = 0.f; racc[t][1] = 0.f; }
    __syncthreads();
    qq = bn >> 5;  // N-tile of 128 lies within one 4096-wide quaternion slab
  }
#pragma unroll
  for (int m = 0; m < 4; ++m) {
#pragma unroll
    for (int r = 0; r < 4; ++r) {
      int rloc = rbase + m * 16 + hi * 4 + r;
      int row = bm * 128 + rloc;
      float bval = 0.f;
      if constexpr (MODE == MODE_GATE) bval = bias[row];
      if constexpr (MODE == MODE_BIAS) bval = bias[bz * M + row];
      float rs = 0.f, rq = 0.f;
#pragma unroll
      for (int n = 0; n < 4; ++n) {
        int col = bn * 128 + cbase + n * 16 + lr;
        float v = acc[m][n][r] + bval;
        if constexpr (MODE == MODE_GATE) {
          v *= aw[((long)bz * 4 + (row & 3)) * N + col];
          // head-grouped: Qh[b][h][g][S]
          C[((long)(bz * 4 + (row & 3)) * 128 + (row >> 2)) * 16384 + col] = f2bf(v);
        } else if constexpr (MODE == MODE_FOLD1) {
          C[((long)(bz >> 2) * 512 + row) * 512 + 4 * col + (bz & 3)] = f2bf(v);
        } else {
          C[(long)bz * sC + (long)row * N + col] = f2bf(v);
        }
        if constexpr (MODE == MODE_BIAS) { rs += v; rq += v * v; }
      }
      if constexpr (MODE == MODE_BIAS) {
        atomicAdd(&racc[rloc][0], rs);
        atomicAdd(&racc[rloc][1], rq);
      }
    }
  }
  if constexpr (MODE == MODE_BIAS) {
    __syncthreads();
    if (t < 128) {
      int c = bm * 128 + t;
      atomicAdd(&stata[(c * 4 + qq) * 2], racc[t][0]);
      atomicAdd(&stata[(c * 4 + qq) * 2 + 1], racc[t][1]);
    }
  }
}

// ---------------- a1 GEMM fused with gate-MLP head + softmax -> aw ----------------
__global__ __launch_bounds__(256, 2) void gemm_a1_aw(const u16* __restrict__ Wa1b, const u16* __restrict__ X1t,
                                                     const float* __restrict__ ba1, const float* __restrict__ Wa2,
                                                     const float* __restrict__ ba2, float* __restrict__ AW) {
  __shared__ union {
    struct { u16 As[2][128 * 64]; u16 Bs[2][128 * 64]; } st;
    float a1s[128][129];
  } u;
  __shared__ float wa2s[512];
  const int t = threadIdx.x;
  const int bn = blockIdx.x, bz = blockIdx.z;
  for (int i = t; i < 512; i += 256) wa2s[i] = Wa2[i];
  const u16* Btile = X1t + (long)bz * 16384 * 512 + (long)(bn * 128) * 512;
  const int wid = t >> 6, l = t & 63;
  const int rbase = (wid >> 1) * 64, cbase = (wid & 1) * 64;
  const int lr = l & 15, hi = l >> 4;
  f32x4 acc[4][4] = {};
#pragma unroll
  for (int i = 0; i < 4; ++i) {
    int idx = t + i * 256;
    int r = idx >> 3;
    int gs = ((idx & 7) ^ (r & 7)) * 8;
    gload_lds16(Wa1b + (long)r * 512 + gs, &u.st.As[0][idx * 8]);
    gload_lds16(Btile + (long)r * 512 + gs, &u.st.Bs[0][idx * 8]);
  }
  __syncthreads();
  int cur = 0;
  for (int kt = 0; kt < 8; ++kt) {
    if (kt < 7) {
      int koff = (kt + 1) << 6;
#pragma unroll
      for (int i = 0; i < 4; ++i) {
        int idx = t + i * 256;
        int r = idx >> 3;
        int gs = ((idx & 7) ^ (r & 7)) * 8;
        gload_lds16(Wa1b + (long)r * 512 + koff + gs, &u.st.As[cur ^ 1][idx * 8]);
        gload_lds16(Btile + (long)r * 512 + koff + gs, &u.st.Bs[cur ^ 1][idx * 8]);
      }
    }
#pragma unroll
    for (int s = 0; s < 2; ++s) {
      bf16x8 av[4], bv[4];
#pragma unroll
      for (int m = 0; m < 4; ++m) {
        int ra = rbase + m * 16 + lr;
        av[m] = *reinterpret_cast<const bf16x8*>(&u.st.As[cur][ra * 64 + ((4 * s + hi) ^ (ra & 7)) * 8]);
      }
#pragma unroll
      for (int n = 0; n < 4; ++n) {
        int rb = cbase + n * 16 + lr;
        bv[n] = *reinterpret_cast<const bf16x8*>(&u.st.Bs[cur][rb * 64 + ((4 * s + hi) ^ (rb & 7)) * 8]);
      }
#pragma unroll
      for (int m = 0; m < 4; ++m)
#pragma unroll
        for (int n = 0; n < 4; ++n)
          acc[m][n] = __builtin_amdgcn_mfma_f32_16x16x32_bf16(av[m], bv[n], acc[m][n], 0, 0, 0);
    }
    __syncthreads();
    cur ^= 1;
  }
  // stash relu(a1) transposed: a1s[pos][ch]
#pragma unroll
  for (int m = 0; m < 4; ++m) {
#pragma unroll
    for (int r = 0; r < 4; ++r) {
      int row = rbase + m * 16 + hi * 4 + r;
      float bval = ba1[row];
#pragma unroll
      for (int n = 0; n < 4; ++n) {
        int col = cbase + n * 16 + lr;
        float v = acc[m][n][r] + bval;
        u.a1s[col][row] = v > 0.f ? v : 0.f;
      }
    }
  }
  __syncthreads();
  if (t < 128) {
    float a0 = ba2[0], a1 = ba2[1], a2 = ba2[2], a3 = ba2[3];
#pragma unroll 4
    for (int c = 0; c < 128; ++c) {
      float av = u.a1s[t][c];
      a0 += wa2s[c] * av; a1 += wa2s[128 + c] * av;
      a2 += wa2s[256 + c] * av; a3 += wa2s[384 + c] * av;
    }
    float mx = fmaxf(fmaxf(a0, a1), fmaxf(a2, a3));
    float e0 = __expf(a0 - mx), e1 = __expf(a1 - mx), e2 = __expf(a2 - mx), e3 = __expf(a3 - mx);
    float inv = 1.f / (e0 + e1 + e2 + e3);
    long sg = (long)bn * 128 + t;
    float* awp = AW + (long)bz * 4 * 16384;
    awp[sg] = e0 * inv;
    awp[16384 + sg] = e1 * inv;
    awp[2 * 16384 + sg] = e2 * inv;
    awp[3 * 16384 + sg] = e3 * inv;
  }
}

// ---------------- logits partials: Lp[ks][bh][g][f] = sum_{s in split} qh*kh ----------------
__global__ __launch_bounds__(256, 2) void logits_k(const u16* __restrict__ Qh, const u16* __restrict__ Kh,
                                                   float* __restrict__ Lp) {
  __shared__ u16 As[2][128 * 64];
  __shared__ u16 Bs[2][128 * 64];
  const long S = 16384;
  const int ks = blockIdx.x;   // 32 splits of 512
  const int bh = blockIdx.y;   // b*4+h
  const int t = threadIdx.x;
  const int wid = t >> 6, l = t & 63;
  const int rbase = (wid >> 1) * 64, cbase = (wid & 1) * 64;
  const int lr = l & 15, hi = l >> 4;
  const u16* qb = Qh + (long)bh * 128 * S + ks * 512;
  const u16* kb = Kh + (long)bh * 128 * S + ks * 512;
  f32x4 acc[4][4] = {};
#pragma unroll
  for (int i = 0; i < 4; ++i) {
    int idx = t + i * 256;
    int r = idx >> 3;
    int gs = ((idx & 7) ^ (r & 7)) * 8;
    gload_lds16(qb + (long)r * S + gs, &As[0][idx * 8]);
    gload_lds16(kb + (long)r * S + gs, &Bs[0][idx * 8]);
  }
  __syncthreads();
  int cur = 0;
  for (int kt = 0; kt < 8; ++kt) {
    if (kt < 7) {
      int koff = (kt + 1) << 6;
#pragma unroll
      for (int i = 0; i < 4; ++i) {
        int idx = t + i * 256;
        int r = idx >> 3;
        int gs = ((idx & 7) ^ (r & 7)) * 8;
        gload_lds16(qb + (long)r * S + koff + gs, &As[cur ^ 1][idx * 8]);
        gload_lds16(kb + (long)r * S + koff + gs, &Bs[cur ^ 1][idx * 8]);
      }
    }
#pragma unroll
    for (int s = 0; s < 2; ++s) {
      bf16x8 av[4], bv[4];
#pragma unroll
      for (int m = 0; m < 4; ++m) {
        int ra = rbase + m * 16 + lr;
        av[m] = *reinterpret_cast<const bf16x8*>(&As[cur][ra * 64 + ((4 * s + hi) ^ (ra & 7)) * 8]);
      }
#pragma unroll
      for (int n = 0; n < 4; ++n) {
        int rb = cbase + n * 16 + lr;
        bv[n] = *reinterpret_cast<const bf16x8*>(&Bs[cur][rb * 64 + ((4 * s + hi) ^ (rb & 7)) * 8]);
      }
#pragma unroll
      for (int m = 0; m < 4; ++m)
#pragma unroll
        for (int n = 0; n < 4; ++n)
          acc[m][n] = __builtin_amdgcn_mfma_f32_16x16x32_bf16(av[m], bv[n], acc[m][n], 0, 0, 0);
    }
    __syncthreads();
    cur ^= 1;
  }
  float* Lb = Lp + ((long)ks * 16 + bh) * 16384;
#pragma unroll
  for (int m = 0; m < 4; ++m)
#pragma unroll
    for (int r = 0; r < 4; ++r) {
      int row = rbase + m * 16 + hi * 4 + r;
#pragma unroll
      for (int n = 0; n < 4; ++n) {
        int col = cbase + n * 16 + lr;
        Lb[row * 128 + col] = acc[m][n][r];
      }
    }
}

// ---------------- reduce partials + softmax rows -> attnT bf16 [bh][f][g] ----------------
__global__ __launch_bounds__(256) void softmax_attnT(const float* __restrict__ Lp, u16* __restrict__ attnT) {
  const float scale = 0.08838834764831845f;  // 1/sqrt(128)
  int row = blockIdx.x * 4 + (threadIdx.x >> 6);  // bh*128+g
  int l = threadIdx.x & 63;
  int bh = row >> 7, g = row & 127;
  const float* base = Lp + (long)bh * 16384 + (long)g * 128;
  float v0 = 0.f, v1 = 0.f;
#pragma unroll 4
  for (int sp = 0; sp < 32; ++sp) {
    v0 += base[(long)sp * 16 * 16384 + l];
    v1 += base[(long)sp * 16 * 16384 + l + 64];
  }
  v0 *= scale; v1 *= scale;
  float m = fmaxf(v0, v1);
  for (int off = 32; off; off >>= 1) m = fmaxf(m, __shfl_xor(m, off));
  float e0 = __expf(v0 - m), e1 = __expf(v1 - m);
  float s = e0 + e1;
  for (int off = 32; off; off >>= 1) s += __shfl_xor(s, off);
  float inv = 1.f / s;
  u16* at = attnT + (long)bh * 16384 + g;
  at[(long)l * 128] = f2bf(e0 * inv);
  at[(long)(l + 64) * 128] = f2bf(e1 * inv);
}

// ---------------- b2[b][o] = bo[o] + sum Weff[b][o][c']*bv[c'] ----------------
__global__ __launch_bounds__(256) void b2_k(const u16* __restrict__ Weff, const float* __restrict__ bv,
                                            const float* __restrict__ bo, float* __restrict__ b2) {
  int idx = blockIdx.x * 256 + threadIdx.x;  // < 2048
  int b = idx >> 9, o = idx & 511;
  const u16* w = Weff + ((long)b * 512 + o) * 512;
  float s = bo[o];
  for (int c = 0; c < 512; ++c) s += bf2f(w[c]) * bv[c];
  b2[idx] = s;
}

// ---------------- normalize (stats from fused accumulators) -> fp32 out ----------------
__global__ __launch_bounds__(256) void norm_k(const u16* __restrict__ o2, const float* __restrict__ stata,
                                              const float* __restrict__ gamma, const float* __restrict__ beta,
                                              float* __restrict__ out) {
  long i8 = ((long)blockIdx.x * 256 + threadIdx.x) * 8;
  int c = (int)((i8 >> 14) & 511);
  int s = (int)(i8 & 16383);
  int g0 = c * 4 + (s >> 12);
  float sum = stata[g0 * 2], sq = stata[g0 * 2 + 1];
  float mean = sum * (1.f / 16384.f);
  float var = sq * (1.f / 16384.f) - mean * mean;
  float inv = rsqrtf(var + 1e-5f);
  float sc = inv * gamma[c];
  float sh = beta[c] - mean * sc;
  uint4 v = *reinterpret_cast<const uint4*>(o2 + i8);
  const unsigned int* pv = reinterpret_cast<const unsigned int*>(&v);
  float4 ra, rb;
  ra.x = bf2f(pv[0] & 0xffffu) * sc + sh; ra.y = bf2f(pv[0] >> 16) * sc + sh;
  ra.z = bf2f(pv[1] & 0xffffu) * sc + sh; ra.w = bf2f(pv[1] >> 16) * sc + sh;
  rb.x = bf2f(pv[2] & 0xffffu) * sc + sh; rb.y = bf2f(pv[2] >> 16) * sc + sh;
  rb.z = bf2f(pv[3] & 0xffffu) * sc + sh; rb.w = bf2f(pv[3] >> 16) * sc + sh;
  *reinterpret_cast<float4*>(out + i8) = ra;
  *reinterpret_cast<float4*>(out + i8 + 4) = rb;
}

extern "C" void kernel_launch(void* const* d_in, const int* in_sizes, int n_in,
                              void* d_out, int out_size, void* d_ws, size_t ws_size,
                              hipStream_t stream) {
  const float* x1 = (const float*)d_in[0];
  const float* x2 = (const float*)d_in[1];
  const float* Wq = (const float*)d_in[2];
  const float* bq = (const float*)d_in[3];
  const float* Wk = (const float*)d_in[4];
  const float* bk = (const float*)d_in[5];
  const float* Wv = (const float*)d_in[6];
  const float* bv = (const float*)d_in[7];
  const float* Wa1 = (const float*)d_in[8];
  const float* ba1 = (const float*)d_in[9];
  const float* Wa2 = (const float*)d_in[10];
  const float* ba2 = (const float*)d_in[11];
  const float* Wo = (const float*)d_in[12];
  const float* bo = (const float*)d_in[13];
  const float* gamma = (const float*)d_in[14];
  const float* beta = (const float*)d_in[15];
  float* out = (float*)d_out;

  char* ws = (char*)d_ws;
  const long MB = 1024L * 1024L;
  u16* X1T = (u16*)(ws);                         // 64MB bf16 [B][S][C]; later Lp (32MB) then O2
  u16* X2T = (u16*)(ws + 64 * MB);               // 64MB
  u16* Qh  = (u16*)(ws + 128 * MB);              // 64MB bf16 [B][4][128][S] head-grouped
  u16* Kh  = (u16*)(ws + 192 * MB);              // 64MB
  float* AW = (float*)(ws + 256 * MB);           // 1MB  [B][4][S]
  float* STATA = (float*)(ws + 257 * MB);        // 16KB [2048][2] sum/sumsq
  u16* ATT  = (u16*)(ws + 258 * MB);             // 0.5MB [16][f][g]
  u16* WEFF = (u16*)(ws + 259 * MB);             // 2MB  [B][512][512]
  u16* W2   = (u16*)(ws + 261 * MB);             // 2MB
  u16* WQB  = (u16*)(ws + 263 * MB);             // 0.5MB
  u16* WKB  = (u16*)(ws + 263 * MB + 512 * 1024);
  u16* WA1B = (u16*)(ws + 264 * MB);             // 128KB
  u16* WVT  = (u16*)(ws + 264 * MB + 256 * 1024);   // 0.5MB
  u16* WOH  = (u16*)(ws + 264 * MB + 768 * 1024);   // 0.5MB [h][o][g]
  float* B2 = (float*)(ws + 265 * MB + 256 * 1024); // 8KB
  float* Lp = (float*)(ws);                      // 32MB, aliases X1T (dead after q-gemm)
  u16* O2 = X1T;                                 // aliases Lp (dead after softmax)
  (void)ws_size; (void)in_sizes; (void)n_in; (void)out_size;

  dim3 blk(256);
  const long SC = (long)16384 * 512;

  // prep
  cvtW_k<<<dim3(576), blk, 0, stream>>>(Wq, Wk, Wa1, WQB, WKB, WA1B);
  woh_k<<<dim3(1024), blk, 0, stream>>>(Wo, WOH);
  transpose_cvt<<<dim3(8, 8, 1), blk, 0, stream>>>(Wv, WVT, 512, 512, 0, 0);
  transpose_cvt<<<dim3(256, 8, 4), blk, 0, stream>>>(x1, X1T, 512, 16384, SC, SC);
  transpose_cvt<<<dim3(256, 8, 4), blk, 0, stream>>>(x2, X2T, 512, 16384, SC, SC);
  hipMemsetAsync(STATA, 0, 2048 * 2 * sizeof(float), stream);

  // gate weights aw
  gemm_a1_aw<<<dim3(128, 1, 4), blk, 0, stream>>>(WA1B, X1T, ba1, Wa2, ba2, AW);

  // q, k (gated, head-grouped output)
  gemm_bt<MODE_GATE><<<dim3(128, 4, 4), blk, 0, stream>>>(WQB, X1T, Qh, bq, AW, nullptr,
                                                          512, 16384, 512, 0L, SC, SC);
  gemm_bt<MODE_GATE><<<dim3(128, 4, 4), blk, 0, stream>>>(WKB, X2T, Kh, bk, AW, nullptr,
                                                          512, 16384, 512, 0L, SC, SC);

  // logits partials + softmax  (Lp lives in X1T's slot, X1T dead now)
  logits_k<<<dim3(32, 16), blk, 0, stream>>>(Qh, Kh, Lp);
  softmax_attnT<<<dim3(512), blk, 0, stream>>>(Lp, ATT);

  // folds: Weff, b2, W2
  gemm_bt<MODE_FOLD1><<<dim3(1, 4, 16), blk, 0, stream>>>(WOH, ATT, WEFF, nullptr, nullptr, nullptr,
                                                          512, 128, 128, 0L, 0L, 0L);
  b2_k<<<dim3(8), blk, 0, stream>>>(WEFF, bv, bo, B2);
  gemm_bt<MODE_PLAIN><<<dim3(4, 4, 4), blk, 0, stream>>>(WEFF, WVT, W2, nullptr, nullptr, nullptr,
                                                         512, 512, 512, 512L * 512L, 0L, 512L * 512L);

  // o2 = W2[b] @ x2 + b2, with fused IQBN partial stats
  gemm_bt<MODE_BIAS><<<dim3(128, 4, 4), blk, 0, stream>>>(W2, X2T, O2, B2, nullptr, STATA,
                                                          512, 16384, 512, 512L * 512L, SC, SC);

  // normalize
  norm_k<<<dim3(16384), blk, 0, stream>>>(O2, STATA, gamma, beta, out);
}